// Round 17
// baseline (22.116 us; speedup 1.0000x reference)
//
#include <hip/hip_runtime.h>
#include <hip/hip_fp16.h>
#include <math.h>

// Problem constants (match reference)
#define Bb   16
#define Cc   3
#define Hh   64
#define Ww   64
#define Kk   32
#define Ss   32
#define OHh  60
#define OWw  60
#define Pp   3600
#define ROWS 34            // staged rows per block: 30 output rows + R-1
#define OHSUB 30
#define NTILE 225          // 15 row-pairs (tr, tr+15) * 15 col-quads
#define TPB  256

// fp16 LDS layout (dword units): row = 33 dwords. Two copies (shift 0/1 col).
// 8-px tile = rows (tr, tr+15) x 4 cols: per leaf-input, dword pairs
// {+0,+1} (row tr) and {+495,+496} (row tr+15) -> 2x ds_read2_b32.
// +495 = bank +15 (odd) -> the two rows cover even+odd banks.
#define DWROW  33
#define DWC    (ROWS * DWROW)   // 1122 dwords per channel
#define DWCOPY (Cc * DWC)       // 3366 dwords per copy
#define ROWOFF (15 * DWROW)     // 495

typedef float vf4 __attribute__((ext_vector_type(4)));
typedef float vf4u __attribute__((ext_vector_type(4), aligned(4)));

#define SB __builtin_amdgcn_sched_barrier(0)

static __device__ __forceinline__ unsigned int pkh(float lo, float hi) {
    __half2 h = __floats2half2_rn(lo, hi);
    return *reinterpret_cast<unsigned int*>(&h);
}
static __device__ __forceinline__ __half2 bc(unsigned int u) {
    return *reinterpret_cast<__half2*>(&u);
}
static __device__ __forceinline__ unsigned int bits(__half2 h) {
    return *reinterpret_cast<unsigned int*>(&h);
}

// fp16 combine on an 8-px tile (uint4 = 4 half2: row tr cols 0-3, row tr+15 cols 0-3)
// coef uint4 = pre-broadcast half2: {c0,c0},{dA,dA},{dB,dB},{dAB,dAB}
static __device__ __forceinline__ uint4 comb4(uint4 a, uint4 b, uint4 c) {
    const __half2 cc0 = bc(c.x), ccA = bc(c.y), ccB = bc(c.z), ccAB = bc(c.w);
    uint4 r;
    r.x = bits(__hfma2(bc(a.x), __hfma2(bc(b.x), ccAB, ccA), __hfma2(bc(b.x), ccB, cc0)));
    r.y = bits(__hfma2(bc(a.y), __hfma2(bc(b.y), ccAB, ccA), __hfma2(bc(b.y), ccB, cc0)));
    r.z = bits(__hfma2(bc(a.z), __hfma2(bc(b.z), ccAB, ccA), __hfma2(bc(b.z), ccB, cc0)));
    r.w = bits(__hfma2(bc(a.w), __hfma2(bc(b.w), ccAB, ccA), __hfma2(bc(b.w), ccB, cc0)));
    return r;
}

// 8-px gather: two dword pairs (rows tr and tr+15) -> 2x ds_read2_b32
#define GR(sb, dst)                                                           \
    {                                                                         \
        dst.x = xsh[(sb) + loff];                                             \
        dst.y = xsh[(sb) + loff + 1];                                         \
        dst.z = xsh[(sb) + loff + ROWOFF];                                    \
        dst.w = xsh[(sb) + loff + ROWOFF + 1];                                \
    }

// prologue: wave-uniform leaf bases -> SGPRs (readfirstlane)
#define RFL(S, J, IDX)                                                        \
    const int sbx##S##_##J = __builtin_amdgcn_readfirstlane(bases[(IDX)].x);  \
    const int sby##S##_##J = __builtin_amdgcn_readfirstlane(bases[(IDX)].y);

// issue stage-S gathers (8 leaf-inputs x 2 ds_read2_b32)
#define PREG(S)                                                               \
    uint4 ga##S##_0, gb##S##_0, ga##S##_1, gb##S##_1;                         \
    uint4 ga##S##_2, gb##S##_2, ga##S##_3, gb##S##_3;                         \
    GR(sbx##S##_0, ga##S##_0); GR(sby##S##_0, gb##S##_0);                     \
    GR(sbx##S##_1, ga##S##_1); GR(sby##S##_1, gb##S##_1);                     \
    GR(sbx##S##_2, ga##S##_2); GR(sby##S##_2, gb##S##_2);                     \
    GR(sbx##S##_3, ga##S##_3); GR(sby##S##_3, gb##S##_3);

// read stage-S coefficients (7 uniform b128, LDS broadcast)
#define COEF(S)                                                               \
    const uint4 kc##S##_0 = coefb[4*(S)],    kc##S##_1 = coefb[4*(S)+1];      \
    const uint4 kc##S##_2 = coefb[4*(S)+2],  kc##S##_3 = coefb[4*(S)+3];      \
    const uint4 kd##S##_0 = coefb[32+2*(S)], kd##S##_1 = coefb[33+2*(S)];     \
    const uint4 ke##S = coefb[48+(S)];

// fp16 FMA tree for stage S (on 8-px tiles)
#define FMAS(S, FOLD)                                                         \
    uint4 t4_##S;                                                             \
    {                                                                         \
        const uint4 u0 = comb4(ga##S##_0, gb##S##_0, kc##S##_0);              \
        const uint4 u1 = comb4(ga##S##_1, gb##S##_1, kc##S##_1);              \
        const uint4 u2 = comb4(ga##S##_2, gb##S##_2, kc##S##_2);              \
        const uint4 u3 = comb4(ga##S##_3, gb##S##_3, kc##S##_3);              \
        t4_##S = comb4(comb4(u0, u1, kd##S##_0), comb4(u2, u3, kd##S##_1), ke##S); \
        FOLD                                                                  \
    }

__global__ __launch_bounds__(TPB) void logic_conv_kernel(
    const float* __restrict__ x,
    const int*   __restrict__ h_idx,
    const int*   __restrict__ w_idx,
    const int*   __restrict__ c_idx,
    const float* __restrict__ w0, const float* __restrict__ w1,
    const float* __restrict__ w2, const float* __restrict__ w3,
    const float* __restrict__ w4, const float* __restrict__ w5,
    float* __restrict__ out)
{
    __shared__ unsigned int xsh[2 * DWCOPY];   // 26,928 B
    __shared__ uint4 coefb[63];                // pre-broadcast half2 coefs
    __shared__ int2  bases[32];

    const int tid  = threadIdx.x;
    const int blk  = blockIdx.x;
    const int b    = blk >> 6;
    const int k    = (blk >> 1) & 31;
    const int half = blk & 1;
    const int oh0  = half * OHSUB;

    // ---- stage rows [oh0, oh0+34) of x[b] as fp16, two shifted copies ----
    const float* xb = x + b * (Cc * Hh * Ww);
    #pragma unroll
    for (int it = 0; it < 7; ++it) {
        const int flat = it * TPB + tid;
        if (flat < Cc * ROWS * 16) {
            const int c   = flat / (ROWS * 16);
            const int rem = flat - c * (ROWS * 16);
            const int r   = rem >> 4;
            const int w4i = rem & 15;
            const int w0c = w4i << 2;
            const float* src = xb + c * (Hh * Ww) + (oh0 + r) * Ww + w0c;
            const vf4u A = *reinterpret_cast<const vf4u*>(src);
            vf4u Bv;
            if (w4i < 15) Bv = *reinterpret_cast<const vf4u*>(src + 1);
            else          Bv = (vf4u){A.y, A.z, A.w, A.w};
            const int di = c * DWC + r * DWROW + (w0c >> 1);
            xsh[di]              = pkh(A.x, A.y);
            xsh[di + 1]          = pkh(A.z, A.w);
            xsh[DWCOPY + di]     = pkh(Bv.x, Bv.y);
            xsh[DWCOPY + di + 1] = pkh(Bv.z, Bv.w);
        }
    }

    // ---- gather bases (dword index, copy by col parity) ----
    if (tid < 32) {
        const int i0 = (0 * Kk + k) * Ss + tid;
        const int i1 = (1 * Kk + k) * Ss + tid;
        const int wA = w_idx[i0], sA = wA & 1;
        const int wB = w_idx[i1], sB = wB & 1;
        bases[tid] = make_int2(
            sA * DWCOPY + c_idx[i0] * DWC + h_idx[i0] * DWROW + ((wA - sA) >> 1),
            sB * DWCOPY + c_idx[i1] * DWC + h_idx[i1] * DWROW + ((wB - sB) >> 1));
    }

    // ---- per-node coefficients: softmax/LUT folded, packed as bcast half2 ----
    if (tid >= 64 && tid < 127) {
        const int t = tid - 64;
        const float* wp; int n;
        if      (t < 32) { wp = w0; n = t;      }
        else if (t < 48) { wp = w1; n = t - 32; }
        else if (t < 56) { wp = w2; n = t - 48; }
        else if (t < 60) { wp = w3; n = t - 56; }
        else if (t < 62) { wp = w4; n = t - 60; }
        else             { wp = w5; n = 0;      }
        const float* lg = wp + (n * Kk + k) * 16;
        float l[16];
        float m = lg[0];
        #pragma unroll
        for (int q = 0; q < 16; ++q) { l[q] = lg[q]; m = fmaxf(m, l[q]); }
        float e[16], s = 0.f;
        #pragma unroll
        for (int q = 0; q < 16; ++q) { e[q] = __expf(l[q] - m); s += e[q]; }
        const float inv = 1.f / s;
        float c0 = 0.f, c1 = 0.f, c2 = 0.f, c3 = 0.f;
        #pragma unroll
        for (int op = 0; op < 16; ++op) {
            if (op & 1) c0 += e[op];
            if (op & 2) c1 += e[op];
            if (op & 4) c2 += e[op];
            if (op & 8) c3 += e[op];
        }
        c0 *= inv; c1 *= inv; c2 *= inv; c3 *= inv;
        const float dA = c2 - c0, dB = c1 - c0, dAB = c0 - c1 - c2 + c3;
        coefb[t] = make_uint4(pkh(c0, c0), pkh(dA, dA), pkh(dB, dB), pkh(dAB, dAB));
    }

    __syncthreads();

    // ---- hoisted wave-uniform leaf bases -> SGPRs ----
    RFL(0,0, 0) RFL(0,1, 1) RFL(0,2, 2) RFL(0,3, 3)
    RFL(1,0, 4) RFL(1,1, 5) RFL(1,2, 6) RFL(1,3, 7)
    RFL(2,0, 8) RFL(2,1, 9) RFL(2,2,10) RFL(2,3,11)
    RFL(3,0,12) RFL(3,1,13) RFL(3,2,14) RFL(3,3,15)
    RFL(4,0,16) RFL(4,1,17) RFL(4,2,18) RFL(4,3,19)
    RFL(5,0,20) RFL(5,1,21) RFL(5,2,22) RFL(5,3,23)
    RFL(6,0,24) RFL(6,1,25) RFL(6,2,26) RFL(6,3,27)
    RFL(7,0,28) RFL(7,1,29) RFL(7,2,30) RFL(7,3,31)

    // ---- main: ONE 8-px tile per thread (rows tr, tr+15 x 4 cols) ----
    if (tid < NTILE) {
        const int tr   = tid % 15;             // row within half-strip
        const int tc   = tid / 15;             // col-quad 0..14
        const int loff = tr * DWROW + (tc << 1);

        uint4 t8a, t8b, t16a, t8a2, t8b2, t16b, y;

        PREG(0)
        COEF(0) PREG(1) SB;
        FMAS(0, )
        COEF(1) PREG(2) SB;
        FMAS(1, t8a = comb4(t4_0, t4_1, coefb[56]);)
        COEF(2) PREG(3) SB;
        FMAS(2, )
        COEF(3) PREG(4) SB;
        FMAS(3, t8b = comb4(t4_2, t4_3, coefb[57]);
                t16a = comb4(t8a, t8b, coefb[60]);)
        COEF(4) PREG(5) SB;
        FMAS(4, )
        COEF(5) PREG(6) SB;
        FMAS(5, t8a2 = comb4(t4_4, t4_5, coefb[58]);)
        COEF(6) PREG(7) SB;
        FMAS(6, )
        COEF(7) SB;
        FMAS(7, t8b2 = comb4(t4_6, t4_7, coefb[59]);
                t16b = comb4(t8a2, t8b2, coefb[61]);
                y = comb4(t16a, t16b, coefb[62]);)
        SB;

        // fp16 -> f32 at store: two float4 rows (tr and tr+15)
        const float2 a0 = __half22float2(bc(y.x));
        const float2 a1 = __half22float2(bc(y.y));
        const float2 b0 = __half22float2(bc(y.z));
        const float2 b1 = __half22float2(bc(y.w));
        float* const outp = out + (b * Kk + k) * Pp + (oh0 + tr) * OWw + (tc << 2);
        *reinterpret_cast<vf4*>(outp)            = (vf4){a0.x, a0.y, a1.x, a1.y};
        *reinterpret_cast<vf4*>(outp + 15 * OWw) = (vf4){b0.x, b0.y, b1.x, b1.y};
    }
}

extern "C" void kernel_launch(void* const* d_in, const int* in_sizes, int n_in,
                              void* d_out, int out_size, void* d_ws, size_t ws_size,
                              hipStream_t stream) {
    const float* x     = (const float*)d_in[0];
    const int*   h_idx = (const int*)d_in[1];
    const int*   w_idx = (const int*)d_in[2];
    const int*   c_idx = (const int*)d_in[3];
    const float* w0    = (const float*)d_in[4];
    const float* w1    = (const float*)d_in[5];
    const float* w2    = (const float*)d_in[6];
    const float* w3    = (const float*)d_in[7];
    const float* w4    = (const float*)d_in[8];
    const float* w5    = (const float*)d_in[9];
    float* out = (float*)d_out;

    dim3 grid(Bb * Kk * 2);   // 1024 blocks: (b, k, row-half)
    dim3 block(TPB);
    hipLaunchKernelGGL(logic_conv_kernel, grid, block, 0, stream,
                       x, h_idx, w_idx, c_idx, w0, w1, w2, w3, w4, w5, out);
}

// Round 18
// 20.706 us; speedup vs baseline: 1.0681x; 1.0681x over previous
//
#include <hip/hip_runtime.h>
#include <hip/hip_fp16.h>
#include <math.h>

// Problem constants (match reference)
#define Bb   16
#define Cc   3
#define Hh   64
#define Ww   64
#define Kk   32
#define Ss   32
#define OHh  60
#define OWw  60
#define Pp   3600
#define ROWS 34            // staged rows per block: 30 output rows + R-1
#define OHSUB 30
#define NGRP 450           // 30 rows * 15 col-quads
#define TPB  512           // 8 waves: ONE 4-px group per thread (halved chain)

// fp16 LDS layout (dword units): row = 33 dwords. Bank stride/row = 1 ->
// oh-major lanes conflict-free. Two copies (shift 0/1 col): every 4-px
// gather is one ds_read2_b32, dwords are direct __half2 operands.
#define DWROW  33
#define DWC    (ROWS * DWROW)   // 1122 dwords per channel
#define DWCOPY (Cc * DWC)       // 3366 dwords per copy

typedef float vf4 __attribute__((ext_vector_type(4)));
typedef float vf4u __attribute__((ext_vector_type(4), aligned(4)));

#define SB __builtin_amdgcn_sched_barrier(0)

static __device__ __forceinline__ unsigned int pkh(float lo, float hi) {
    __half2 h = __floats2half2_rn(lo, hi);
    return *reinterpret_cast<unsigned int*>(&h);
}
static __device__ __forceinline__ __half2 bc(unsigned int u) {
    return *reinterpret_cast<__half2*>(&u);
}
static __device__ __forceinline__ unsigned int bits(__half2 h) {
    return *reinterpret_cast<unsigned int*>(&h);
}

// fp16 combine on 4 px (2 half2): y = c0 + a*dA + b*dB + a*b*dAB
// coef uint4 = pre-broadcast half2: {c0,c0},{dA,dA},{dB,dB},{dAB,dAB}
static __device__ __forceinline__ uint2 comb2(uint2 a, uint2 b, uint4 c) {
    const __half2 cc0 = bc(c.x), ccA = bc(c.y), ccB = bc(c.z), ccAB = bc(c.w);
    const __half2 tx = __hfma2(bc(b.x), ccAB, ccA);
    const __half2 ty = __hfma2(bc(b.y), ccAB, ccA);
    const __half2 ux = __hfma2(bc(b.x), ccB, cc0);
    const __half2 uy = __hfma2(bc(b.y), ccB, cc0);
    uint2 r;
    r.x = bits(__hfma2(bc(a.x), tx, ux));
    r.y = bits(__hfma2(bc(a.y), ty, uy));
    return r;
}

// raw gather: two adjacent dwords -> one ds_read2_b32 (base is SGPR-resident)
#define GR(sb, dst) { dst.x = xsh[(sb) + loff]; dst.y = xsh[(sb) + loff + 1]; }

// prologue: wave-uniform leaf bases -> SGPRs (readfirstlane)
#define RFL(S, J, IDX)                                                        \
    const int sbx##S##_##J = __builtin_amdgcn_readfirstlane(bases[(IDX)].x);  \
    const int sby##S##_##J = __builtin_amdgcn_readfirstlane(bases[(IDX)].y);

// issue stage-S gathers (8 ds_read2_b32)
#define PREG(S)                                                               \
    uint2 ga##S##_0, gb##S##_0, ga##S##_1, gb##S##_1;                         \
    uint2 ga##S##_2, gb##S##_2, ga##S##_3, gb##S##_3;                         \
    GR(sbx##S##_0, ga##S##_0); GR(sby##S##_0, gb##S##_0);                     \
    GR(sbx##S##_1, ga##S##_1); GR(sby##S##_1, gb##S##_1);                     \
    GR(sbx##S##_2, ga##S##_2); GR(sby##S##_2, gb##S##_2);                     \
    GR(sbx##S##_3, ga##S##_3); GR(sby##S##_3, gb##S##_3);

// read stage-S coefficients (7 uniform b128, LDS broadcast)
#define COEF(S)                                                               \
    const uint4 kc##S##_0 = coefb[4*(S)],    kc##S##_1 = coefb[4*(S)+1];      \
    const uint4 kc##S##_2 = coefb[4*(S)+2],  kc##S##_3 = coefb[4*(S)+3];      \
    const uint4 kd##S##_0 = coefb[32+2*(S)], kd##S##_1 = coefb[33+2*(S)];     \
    const uint4 ke##S = coefb[48+(S)];

// fp16 FMA tree for stage S
#define FMAS(S, FOLD)                                                         \
    uint2 t4_##S;                                                             \
    {                                                                         \
        const uint2 u0 = comb2(ga##S##_0, gb##S##_0, kc##S##_0);              \
        const uint2 u1 = comb2(ga##S##_1, gb##S##_1, kc##S##_1);              \
        const uint2 u2 = comb2(ga##S##_2, gb##S##_2, kc##S##_2);              \
        const uint2 u3 = comb2(ga##S##_3, gb##S##_3, kc##S##_3);              \
        t4_##S = comb2(comb2(u0, u1, kd##S##_0), comb2(u2, u3, kd##S##_1), ke##S); \
        FOLD                                                                  \
    }

__global__ __launch_bounds__(TPB) void logic_conv_kernel(
    const float* __restrict__ x,
    const int*   __restrict__ h_idx,
    const int*   __restrict__ w_idx,
    const int*   __restrict__ c_idx,
    const float* __restrict__ w0, const float* __restrict__ w1,
    const float* __restrict__ w2, const float* __restrict__ w3,
    const float* __restrict__ w4, const float* __restrict__ w5,
    float* __restrict__ out)
{
    __shared__ unsigned int xsh[2 * DWCOPY];   // 26,928 B
    __shared__ uint4 coefb[63];                // pre-broadcast half2 coefs
    __shared__ int2  bases[32];

    const int tid  = threadIdx.x;
    const int blk  = blockIdx.x;
    const int b    = blk >> 6;
    const int k    = (blk >> 1) & 31;
    const int half = blk & 1;
    const int oh0  = half * OHSUB;

    // ---- stage rows [oh0, oh0+34) of x[b] as fp16, two shifted copies ----
    const float* xb = x + b * (Cc * Hh * Ww);
    #pragma unroll
    for (int it = 0; it < 4; ++it) {
        const int flat = it * TPB + tid;
        if (flat < Cc * ROWS * 16) {
            const int c   = flat / (ROWS * 16);
            const int rem = flat - c * (ROWS * 16);
            const int r   = rem >> 4;
            const int w4i = rem & 15;
            const int w0c = w4i << 2;
            const float* src = xb + c * (Hh * Ww) + (oh0 + r) * Ww + w0c;
            const vf4u A = *reinterpret_cast<const vf4u*>(src);
            vf4u Bv;
            if (w4i < 15) Bv = *reinterpret_cast<const vf4u*>(src + 1);
            else          Bv = (vf4u){A.y, A.z, A.w, A.w};
            const int di = c * DWC + r * DWROW + (w0c >> 1);
            xsh[di]              = pkh(A.x, A.y);
            xsh[di + 1]          = pkh(A.z, A.w);
            xsh[DWCOPY + di]     = pkh(Bv.x, Bv.y);
            xsh[DWCOPY + di + 1] = pkh(Bv.z, Bv.w);
        }
    }

    // ---- gather bases (dword index, copy by col parity) ----
    if (tid < 32) {
        const int i0 = (0 * Kk + k) * Ss + tid;
        const int i1 = (1 * Kk + k) * Ss + tid;
        const int wA = w_idx[i0], sA = wA & 1;
        const int wB = w_idx[i1], sB = wB & 1;
        bases[tid] = make_int2(
            sA * DWCOPY + c_idx[i0] * DWC + h_idx[i0] * DWROW + ((wA - sA) >> 1),
            sB * DWCOPY + c_idx[i1] * DWC + h_idx[i1] * DWROW + ((wB - sB) >> 1));
    }

    // ---- per-node coefficients: softmax/LUT folded, packed as bcast half2 ----
    if (tid >= 64 && tid < 127) {
        const int t = tid - 64;
        const float* wp; int n;
        if      (t < 32) { wp = w0; n = t;      }
        else if (t < 48) { wp = w1; n = t - 32; }
        else if (t < 56) { wp = w2; n = t - 48; }
        else if (t < 60) { wp = w3; n = t - 56; }
        else if (t < 62) { wp = w4; n = t - 60; }
        else             { wp = w5; n = 0;      }
        const float* lg = wp + (n * Kk + k) * 16;
        float l[16];
        float m = lg[0];
        #pragma unroll
        for (int q = 0; q < 16; ++q) { l[q] = lg[q]; m = fmaxf(m, l[q]); }
        float e[16], s = 0.f;
        #pragma unroll
        for (int q = 0; q < 16; ++q) { e[q] = __expf(l[q] - m); s += e[q]; }
        const float inv = 1.f / s;
        float c0 = 0.f, c1 = 0.f, c2 = 0.f, c3 = 0.f;
        #pragma unroll
        for (int op = 0; op < 16; ++op) {
            if (op & 1) c0 += e[op];
            if (op & 2) c1 += e[op];
            if (op & 4) c2 += e[op];
            if (op & 8) c3 += e[op];
        }
        c0 *= inv; c1 *= inv; c2 *= inv; c3 *= inv;
        const float dA = c2 - c0, dB = c1 - c0, dAB = c0 - c1 - c2 + c3;
        coefb[t] = make_uint4(pkh(c0, c0), pkh(dA, dA), pkh(dB, dB), pkh(dAB, dAB));
    }

    __syncthreads();

    // ---- hoisted wave-uniform leaf bases -> SGPRs ----
    RFL(0,0, 0) RFL(0,1, 1) RFL(0,2, 2) RFL(0,3, 3)
    RFL(1,0, 4) RFL(1,1, 5) RFL(1,2, 6) RFL(1,3, 7)
    RFL(2,0, 8) RFL(2,1, 9) RFL(2,2,10) RFL(2,3,11)
    RFL(3,0,12) RFL(3,1,13) RFL(3,2,14) RFL(3,3,15)
    RFL(4,0,16) RFL(4,1,17) RFL(4,2,18) RFL(4,3,19)
    RFL(5,0,20) RFL(5,1,21) RFL(5,2,22) RFL(5,3,23)
    RFL(6,0,24) RFL(6,1,25) RFL(6,2,26) RFL(6,3,27)
    RFL(7,0,28) RFL(7,1,29) RFL(7,2,30) RFL(7,3,31)

    // ---- main: ONE 4-px group per thread (halved per-wave critical path) ----
    if (tid < NGRP) {
        const int oh   = tid % OHSUB;          // consecutive lanes -> rows
        const int owg  = tid / OHSUB;          // 0..14
        const int loff = oh * DWROW + (owg << 1);

        uint2 t8a, t8b, t16a, t8a2, t8b2, t16b, y;

        PREG(0)
        COEF(0) PREG(1) SB;
        FMAS(0, )
        COEF(1) PREG(2) SB;
        FMAS(1, t8a = comb2(t4_0, t4_1, coefb[56]);)
        COEF(2) PREG(3) SB;
        FMAS(2, )
        COEF(3) PREG(4) SB;
        FMAS(3, t8b = comb2(t4_2, t4_3, coefb[57]);
                t16a = comb2(t8a, t8b, coefb[60]);)
        COEF(4) PREG(5) SB;
        FMAS(4, )
        COEF(5) PREG(6) SB;
        FMAS(5, t8a2 = comb2(t4_4, t4_5, coefb[58]);)
        COEF(6) PREG(7) SB;
        FMAS(6, )
        COEF(7) SB;
        FMAS(7, t8b2 = comb2(t4_6, t4_7, coefb[59]);
                t16b = comb2(t8a2, t8b2, coefb[61]);
                y = comb2(t16a, t16b, coefb[62]);)
        SB;

        // fp16 -> f32 only at the output store
        const float2 ylo = __half22float2(bc(y.x));
        const float2 yhi = __half22float2(bc(y.y));
        float* const outp = out + (b * Kk + k) * Pp + (oh0 + oh) * OWw + (owg << 2);
        *reinterpret_cast<vf4*>(outp) = (vf4){ylo.x, ylo.y, yhi.x, yhi.y};
    }
}

extern "C" void kernel_launch(void* const* d_in, const int* in_sizes, int n_in,
                              void* d_out, int out_size, void* d_ws, size_t ws_size,
                              hipStream_t stream) {
    const float* x     = (const float*)d_in[0];
    const int*   h_idx = (const int*)d_in[1];
    const int*   w_idx = (const int*)d_in[2];
    const int*   c_idx = (const int*)d_in[3];
    const float* w0    = (const float*)d_in[4];
    const float* w1    = (const float*)d_in[5];
    const float* w2    = (const float*)d_in[6];
    const float* w3    = (const float*)d_in[7];
    const float* w4    = (const float*)d_in[8];
    const float* w5    = (const float*)d_in[9];
    float* out = (float*)d_out;

    dim3 grid(Bb * Kk * 2);   // 1024 blocks: (b, k, row-half)
    dim3 block(TPB);
    hipLaunchKernelGGL(logic_conv_kernel, grid, block, 0, stream,
                       x, h_idx, w_idx, c_idx, w0, w1, w2, w3, w4, w5, out);
}

// Round 19
// 20.587 us; speedup vs baseline: 1.0743x; 1.0058x over previous
//
#include <hip/hip_runtime.h>
#include <hip/hip_fp16.h>
#include <math.h>

// Problem constants (match reference)
#define Bb   16
#define Cc   3
#define Hh   64
#define Ww   64
#define Kk   32
#define Ss   32
#define OHh  60
#define OWw  60
#define Pp   3600
#define ROWS 34            // staged rows per block: 30 output rows + R-1
#define OHSUB 30
#define NGRP 450           // 30 rows * 15 col-quads (per k)
#define TPB  512

// fp16 LDS layout (dword units): row = 33 dwords. Bank stride/row = 1 ->
// oh-major lanes conflict-free. Two copies (shift 0/1 col): every 4-px
// gather is one ds_read2_b32, dwords are direct __half2 operands.
#define DWROW  33
#define DWC    (ROWS * DWROW)   // 1122 dwords per channel
#define DWCOPY (Cc * DWC)       // 3366 dwords per copy

typedef float vf4 __attribute__((ext_vector_type(4)));
typedef float vf4u __attribute__((ext_vector_type(4), aligned(4)));

#define SB __builtin_amdgcn_sched_barrier(0)

static __device__ __forceinline__ unsigned int pkh(float lo, float hi) {
    __half2 h = __floats2half2_rn(lo, hi);
    return *reinterpret_cast<unsigned int*>(&h);
}
static __device__ __forceinline__ __half2 bc(unsigned int u) {
    return *reinterpret_cast<__half2*>(&u);
}
static __device__ __forceinline__ unsigned int bits(__half2 h) {
    return *reinterpret_cast<unsigned int*>(&h);
}

// fp16 combine on 4 px (2 half2): y = c0 + a*dA + b*dB + a*b*dAB
// coef uint4 = pre-broadcast half2: {c0,c0},{dA,dA},{dB,dB},{dAB,dAB}
static __device__ __forceinline__ uint2 comb2(uint2 a, uint2 b, uint4 c) {
    const __half2 cc0 = bc(c.x), ccA = bc(c.y), ccB = bc(c.z), ccAB = bc(c.w);
    const __half2 tx = __hfma2(bc(b.x), ccAB, ccA);
    const __half2 ty = __hfma2(bc(b.y), ccAB, ccA);
    const __half2 ux = __hfma2(bc(b.x), ccB, cc0);
    const __half2 uy = __hfma2(bc(b.y), ccB, cc0);
    uint2 r;
    r.x = bits(__hfma2(bc(a.x), tx, ux));
    r.y = bits(__hfma2(bc(a.y), ty, uy));
    return r;
}

// raw gather: two adjacent dwords -> one ds_read2_b32 (base is SGPR-resident)
#define GR(sb, dst) { dst.x = xsh[(sb) + loff]; dst.y = xsh[(sb) + loff + 1]; }

// wave-uniform leaf bases -> SGPRs (readfirstlane); boff selects k
#define RFL(S, J, IDX)                                                        \
    const int sbx##S##_##J = __builtin_amdgcn_readfirstlane(bases[boff + (IDX)].x); \
    const int sby##S##_##J = __builtin_amdgcn_readfirstlane(bases[boff + (IDX)].y);

// issue stage-S gathers (8 ds_read2_b32)
#define PREG(S)                                                               \
    uint2 ga##S##_0, gb##S##_0, ga##S##_1, gb##S##_1;                         \
    uint2 ga##S##_2, gb##S##_2, ga##S##_3, gb##S##_3;                         \
    GR(sbx##S##_0, ga##S##_0); GR(sby##S##_0, gb##S##_0);                     \
    GR(sbx##S##_1, ga##S##_1); GR(sby##S##_1, gb##S##_1);                     \
    GR(sbx##S##_2, ga##S##_2); GR(sby##S##_2, gb##S##_2);                     \
    GR(sbx##S##_3, ga##S##_3); GR(sby##S##_3, gb##S##_3);

// read stage-S coefficients (7 uniform b128); koff selects k
#define COEF(S)                                                               \
    const uint4 kc##S##_0 = coefb[koff + 4*(S)],    kc##S##_1 = coefb[koff + 4*(S)+1]; \
    const uint4 kc##S##_2 = coefb[koff + 4*(S)+2],  kc##S##_3 = coefb[koff + 4*(S)+3]; \
    const uint4 kd##S##_0 = coefb[koff + 32+2*(S)], kd##S##_1 = coefb[koff + 33+2*(S)]; \
    const uint4 ke##S = coefb[koff + 48+(S)];

// fp16 FMA tree for stage S
#define FMAS(S, FOLD)                                                         \
    uint2 t4_##S;                                                             \
    {                                                                         \
        const uint2 u0 = comb2(ga##S##_0, gb##S##_0, kc##S##_0);              \
        const uint2 u1 = comb2(ga##S##_1, gb##S##_1, kc##S##_1);              \
        const uint2 u2 = comb2(ga##S##_2, gb##S##_2, kc##S##_2);              \
        const uint2 u3 = comb2(ga##S##_3, gb##S##_3, kc##S##_3);              \
        t4_##S = comb2(comb2(u0, u1, kd##S##_0), comb2(u2, u3, kd##S##_1), ke##S); \
        FOLD                                                                  \
    }

__global__ __launch_bounds__(TPB) void logic_conv_kernel(
    const float* __restrict__ x,
    const int*   __restrict__ h_idx,
    const int*   __restrict__ w_idx,
    const int*   __restrict__ c_idx,
    const float* __restrict__ w0, const float* __restrict__ w1,
    const float* __restrict__ w2, const float* __restrict__ w3,
    const float* __restrict__ w4, const float* __restrict__ w5,
    float* __restrict__ out)
{
    __shared__ unsigned int xsh[2 * DWCOPY];   // 26,928 B
    __shared__ uint4 coefb[126];               // 2 k's of pre-broadcast coefs
    __shared__ int2  bases[64];                // 2 k's of leaf bases

    const int tid  = threadIdx.x;
    const int blk  = blockIdx.x;
    const int kp   = blk & 15;                 // k-pair index
    const int half = (blk >> 4) & 1;
    const int b    = blk >> 5;
    const int k0   = kp << 1;
    const int oh0  = half * OHSUB;

    // ---- stage rows [oh0, oh0+34) of x[b] as fp16, two shifted copies ----
    const float* xb = x + b * (Cc * Hh * Ww);
    #pragma unroll
    for (int it = 0; it < 4; ++it) {
        const int flat = it * TPB + tid;
        if (flat < Cc * ROWS * 16) {
            const int c   = flat / (ROWS * 16);
            const int rem = flat - c * (ROWS * 16);
            const int r   = rem >> 4;
            const int w4i = rem & 15;
            const int w0c = w4i << 2;
            const float* src = xb + c * (Hh * Ww) + (oh0 + r) * Ww + w0c;
            const vf4u A = *reinterpret_cast<const vf4u*>(src);
            vf4u Bv;
            if (w4i < 15) Bv = *reinterpret_cast<const vf4u*>(src + 1);
            else          Bv = (vf4u){A.y, A.z, A.w, A.w};
            const int di = c * DWC + r * DWROW + (w0c >> 1);
            xsh[di]              = pkh(A.x, A.y);
            xsh[di + 1]          = pkh(A.z, A.w);
            xsh[DWCOPY + di]     = pkh(Bv.x, Bv.y);
            xsh[DWCOPY + di + 1] = pkh(Bv.z, Bv.w);
        }
    }

    // ---- gather bases for BOTH k's (dword index, copy by col parity) ----
    if (tid < 64) {
        const int kk   = tid >> 5;             // 0/1
        const int leaf = tid & 31;
        const int kcur = k0 + kk;
        const int i0 = (0 * Kk + kcur) * Ss + leaf;
        const int i1 = (1 * Kk + kcur) * Ss + leaf;
        const int wA = w_idx[i0], sA = wA & 1;
        const int wB = w_idx[i1], sB = wB & 1;
        bases[tid] = make_int2(
            sA * DWCOPY + c_idx[i0] * DWC + h_idx[i0] * DWROW + ((wA - sA) >> 1),
            sB * DWCOPY + c_idx[i1] * DWC + h_idx[i1] * DWROW + ((wB - sB) >> 1));
    }

    // ---- per-node coefficients for BOTH k's (waves 1 and 2) ----
    {
        int t = -1, kk = 0;
        if (tid >= 64 && tid < 127)       { t = tid - 64;  kk = 0; }
        else if (tid >= 128 && tid < 191) { t = tid - 128; kk = 1; }
        if (t >= 0) {
            const int kcur = k0 + kk;
            const float* wp; int n;
            if      (t < 32) { wp = w0; n = t;      }
            else if (t < 48) { wp = w1; n = t - 32; }
            else if (t < 56) { wp = w2; n = t - 48; }
            else if (t < 60) { wp = w3; n = t - 56; }
            else if (t < 62) { wp = w4; n = t - 60; }
            else             { wp = w5; n = 0;      }
            const float* lg = wp + (n * Kk + kcur) * 16;
            float l[16];
            float m = lg[0];
            #pragma unroll
            for (int q = 0; q < 16; ++q) { l[q] = lg[q]; m = fmaxf(m, l[q]); }
            float e[16], s = 0.f;
            #pragma unroll
            for (int q = 0; q < 16; ++q) { e[q] = __expf(l[q] - m); s += e[q]; }
            const float inv = 1.f / s;
            float c0 = 0.f, c1 = 0.f, c2 = 0.f, c3 = 0.f;
            #pragma unroll
            for (int op = 0; op < 16; ++op) {
                if (op & 1) c0 += e[op];
                if (op & 2) c1 += e[op];
                if (op & 4) c2 += e[op];
                if (op & 8) c3 += e[op];
            }
            c0 *= inv; c1 *= inv; c2 *= inv; c3 *= inv;
            const float dA = c2 - c0, dB = c1 - c0, dAB = c0 - c1 - c2 + c3;
            coefb[kk * 63 + t] =
                make_uint4(pkh(c0, c0), pkh(dA, dA), pkh(dB, dB), pkh(dAB, dAB));
        }
    }

    __syncthreads();

    // ---- main: run the 8-stage tree for k0 then k1 on the same staged x ----
    if (tid < NGRP) {
        const int oh   = tid % OHSUB;          // consecutive lanes -> rows
        const int owg  = tid / OHSUB;          // 0..14
        const int loff = oh * DWROW + (owg << 1);

        #pragma unroll
        for (int kk = 0; kk < 2; ++kk) {
            const int koff = kk * 63;
            const int boff = kk * 32;

            RFL(0,0, 0) RFL(0,1, 1) RFL(0,2, 2) RFL(0,3, 3)
            RFL(1,0, 4) RFL(1,1, 5) RFL(1,2, 6) RFL(1,3, 7)
            RFL(2,0, 8) RFL(2,1, 9) RFL(2,2,10) RFL(2,3,11)
            RFL(3,0,12) RFL(3,1,13) RFL(3,2,14) RFL(3,3,15)
            RFL(4,0,16) RFL(4,1,17) RFL(4,2,18) RFL(4,3,19)
            RFL(5,0,20) RFL(5,1,21) RFL(5,2,22) RFL(5,3,23)
            RFL(6,0,24) RFL(6,1,25) RFL(6,2,26) RFL(6,3,27)
            RFL(7,0,28) RFL(7,1,29) RFL(7,2,30) RFL(7,3,31)

            uint2 t8a, t8b, t16a, t8a2, t8b2, t16b, y;

            PREG(0)
            COEF(0) PREG(1) SB;
            FMAS(0, )
            COEF(1) PREG(2) SB;
            FMAS(1, t8a = comb2(t4_0, t4_1, coefb[koff + 56]);)
            COEF(2) PREG(3) SB;
            FMAS(2, )
            COEF(3) PREG(4) SB;
            FMAS(3, t8b = comb2(t4_2, t4_3, coefb[koff + 57]);
                    t16a = comb2(t8a, t8b, coefb[koff + 60]);)
            COEF(4) PREG(5) SB;
            FMAS(4, )
            COEF(5) PREG(6) SB;
            FMAS(5, t8a2 = comb2(t4_4, t4_5, coefb[koff + 58]);)
            COEF(6) PREG(7) SB;
            FMAS(6, )
            COEF(7) SB;
            FMAS(7, t8b2 = comb2(t4_6, t4_7, coefb[koff + 59]);
                    t16b = comb2(t8a2, t8b2, coefb[koff + 61]);
                    y = comb2(t16a, t16b, coefb[koff + 62]);)
            SB;

            // fp16 -> f32 only at the output store
            const float2 ylo = __half22float2(bc(y.x));
            const float2 yhi = __half22float2(bc(y.y));
            float* const outp = out + (b * Kk + k0 + kk) * Pp
                                    + (oh0 + oh) * OWw + (owg << 2);
            *reinterpret_cast<vf4*>(outp) = (vf4){ylo.x, ylo.y, yhi.x, yhi.y};
        }
    }
}

extern "C" void kernel_launch(void* const* d_in, const int* in_sizes, int n_in,
                              void* d_out, int out_size, void* d_ws, size_t ws_size,
                              hipStream_t stream) {
    const float* x     = (const float*)d_in[0];
    const int*   h_idx = (const int*)d_in[1];
    const int*   w_idx = (const int*)d_in[2];
    const int*   c_idx = (const int*)d_in[3];
    const float* w0    = (const float*)d_in[4];
    const float* w1    = (const float*)d_in[5];
    const float* w2    = (const float*)d_in[6];
    const float* w3    = (const float*)d_in[7];
    const float* w4    = (const float*)d_in[8];
    const float* w5    = (const float*)d_in[9];
    float* out = (float*)d_out;

    dim3 grid(Bb * 2 * (Kk / 2));   // 512 blocks: (b, half, k-pair)
    dim3 block(TPB);
    hipLaunchKernelGGL(logic_conv_kernel, grid, block, 0, stream,
                       x, h_idx, w_idx, c_idx, w0, w1, w2, w3, w4, w5, out);
}